// Round 7
// baseline (3619.526 us; speedup 1.0000x reference)
//
#include <hip/hip_runtime.h>
#include <math.h>

#define N_NODES 50000
#define NUM_EDGES 800000
#define NG 8
#define HID 256
#define RHD 128
#define NEXP 4
#define OUTD 6

// ---------------- zero init (graph-capture-safe) ----------------
__global__ void k_zero(int* __restrict__ deg, int* __restrict__ n_cnt,
                       int* __restrict__ e_cnt) {
  int i = blockIdx.x * blockDim.x + threadIdx.x;
  if (i < N_NODES) deg[i] = 0;
  if (i < NG) { n_cnt[i] = 0; e_cnt[i] = 0; }
}

// ---------------- graph stats ----------------
__global__ void k_count_nodes(const int* __restrict__ batch, int* __restrict__ n_cnt) {
  __shared__ int hist[NG];
  int t = threadIdx.x;
  if (t < NG) hist[t] = 0;
  __syncthreads();
  int i = blockIdx.x * blockDim.x + t;
  if (i < N_NODES) atomicAdd(&hist[batch[i]], 1);
  __syncthreads();
  if (t < NG && hist[t]) atomicAdd(&n_cnt[t], hist[t]);
}

__global__ void k_count_edges(const int* __restrict__ edge, const int* __restrict__ batch,
                              int* __restrict__ e_cnt, int* __restrict__ deg) {
  __shared__ int hist[NG];
  int t = threadIdx.x;
  if (t < NG) hist[t] = 0;
  __syncthreads();
  int i = blockIdx.x * blockDim.x + t;
  if (i < NUM_EDGES) {
    int s = edge[i];               // src row
    int d = edge[NUM_EDGES + i];   // dst row
    atomicAdd(&hist[batch[s]], 1);
    atomicAdd(&deg[d], 1);
  }
  __syncthreads();
  if (t < NG && hist[t]) atomicAdd(&e_cnt[t], hist[t]);
}

// numpy-faithful f32 stats: f64 log/log1p rounded to f32 (≈ correctly-rounded = np u10),
// numpy pairwise tree for the 8-element means, true divisions, no fp-contraction.
__device__ __forceinline__ float tree8(const float* v) {
  float s01 = __fadd_rn(v[0], v[1]);
  float s23 = __fadd_rn(v[2], v[3]);
  float s45 = __fadd_rn(v[4], v[5]);
  float s67 = __fadd_rn(v[6], v[7]);
  return __fadd_rn(__fadd_rn(s01, s23), __fadd_rn(s45, s67));
}

__global__ void k_graph_stats(const int* __restrict__ n_cnt, const int* __restrict__ e_cnt,
                              float* __restrict__ gf, float* __restrict__ lnn) {
  if (threadIdx.x != 0 || blockIdx.x != 0) return;
  float logn[NG], loge[NG];
  for (int g = 0; g < NG; ++g) {
    float nf = fmaxf((float)n_cnt[g], 1.0f);
    logn[g] = (float)log((double)nf);          // np.log(float32): ~correctly rounded
    float ef = fmaxf((float)e_cnt[g], 0.0f);
    loge[g] = (float)log1p((double)ef);        // np.log1p
  }
  float m0 = __fdiv_rn(tree8(logn), 8.0f);
  float m1 = __fdiv_rn(tree8(loge), 8.0f);
  float sq0[NG], sq1[NG];
  float mn = 3.0e38f, mx = -3.0e38f;
  for (int g = 0; g < NG; ++g) {
    float d0 = __fsub_rn(logn[g], m0);
    float d1 = __fsub_rn(loge[g], m1);
    sq0[g] = __fmul_rn(d0, d0);
    sq1[g] = __fmul_rn(d1, d1);
    mn = fminf(mn, logn[g]); mx = fmaxf(mx, logn[g]);
  }
  float s0 = __fadd_rn(sqrtf(__fdiv_rn(tree8(sq0), 8.0f)), 1e-6f);
  float s1 = __fadd_rn(sqrtf(__fdiv_rn(tree8(sq1), 8.0f)), 1e-6f);
  float denom = __fadd_rn(__fsub_rn(mx, mn), 1e-6f);
  for (int g = 0; g < NG; ++g) {
    gf[g * 2 + 0] = __fdiv_rn(__fsub_rn(logn[g], m0), s0);
    gf[g * 2 + 1] = __fdiv_rn(__fsub_rn(loge[g], m1), s1);
    lnn[g] = __fdiv_rn(__fsub_rn(logn[g], mn), denom);
  }
}

// ---------------- CSR build ----------------
__global__ void k_scan(const int* __restrict__ deg, int* __restrict__ row_start,
                       int* __restrict__ cursor) {
  __shared__ int temp[1024];
  int tid = threadIdx.x;
  int carry = 0;
  for (int base = 0; base < N_NODES; base += 1024) {
    int i = base + tid;
    int v = (i < N_NODES) ? deg[i] : 0;
    temp[tid] = v;
    __syncthreads();
    for (int off = 1; off < 1024; off <<= 1) {
      int t = (tid >= off) ? temp[tid - off] : 0;
      __syncthreads();
      temp[tid] += t;
      __syncthreads();
    }
    int incl = temp[tid];
    if (i < N_NODES) {
      int e = carry + incl - v;
      row_start[i] = e;
      cursor[i] = e;
    }
    carry += temp[1023];
    __syncthreads();
  }
  if (tid == 0) row_start[N_NODES] = carry;
}

__global__ void k_fill(const int* __restrict__ edge, int* __restrict__ cursor,
                       int* __restrict__ csr_src) {
  int i = blockIdx.x * blockDim.x + threadIdx.x;
  if (i < NUM_EDGES) {
    int d = edge[NUM_EDGES + i];
    int p = atomicAdd(&cursor[d], 1);
    csr_src[p] = edge[i];
  }
}

// ---------------- encoder layer 1: t = relu(xs @ W1 + b1), fp32, bias-last ---------
__global__ void k_enc1(const float* __restrict__ x, const float* __restrict__ w1,
                       const float* __restrict__ b1, float* __restrict__ t) {
  __shared__ float W[6 * 256];
  __shared__ float xs[16][6];
  int tid = threadIdx.x;
  for (int i = tid; i < 6 * 256; i += 256) W[i] = w1[i];
  int base = blockIdx.x * 16;
  if (tid < 96) {
    int n = tid / 6, k = tid % 6;
    int node = base + n;
    xs[n][k] = (node < N_NODES) ? x[node * 16 + 4 + k] : 0.f;
  }
  __syncthreads();
  float b = b1[tid];
  for (int n = 0; n < 16; ++n) {
    int node = base + n;
    if (node >= N_NODES) break;
    float acc = 0.f;
#pragma unroll
    for (int k = 0; k < 6; ++k) acc = __fmaf_rn(xs[n][k], W[k * 256 + tid], acc);
    t[node * 256 + tid] = fmaxf(__fadd_rn(acc, b), 0.f);
  }
}

// ---------------- generic 256-col GEMM: C = act(A@W0 (+ B@W1) + bias), fp32 --------
// Single ascending FMA chain per element (sgemm-like), bias added at the end.
template <bool RELU, bool HASB>
__global__ __launch_bounds__(256, 2) void k_gemm(
    const float* __restrict__ A, const float* __restrict__ W0,
    const float* __restrict__ B, const float* __restrict__ W1,
    const float* __restrict__ bias, float* __restrict__ C, int M) {
  __shared__ float As[16][132];   // [k][m], +4 pad
  __shared__ float Ws[16][128];   // [k][n]
  const int tid = threadIdx.x;
  const int tx = tid & 15;
  const int ty = tid >> 4;
  const int rowBase = blockIdx.x * 128;
  const int colBase = blockIdx.y * 128;

  float acc[2][2][4][4];
#pragma unroll
  for (int a = 0; a < 2; ++a)
#pragma unroll
    for (int b = 0; b < 2; ++b)
#pragma unroll
      for (int i = 0; i < 4; ++i)
#pragma unroll
        for (int j = 0; j < 4; ++j) acc[a][b][i][j] = 0.f;

  const int NPHASE = HASB ? 2 : 1;
  for (int phase = 0; phase < NPHASE; ++phase) {
    const float* __restrict__ Ain = phase ? B : A;
    const float* __restrict__ Win = phase ? W1 : W0;
    for (int kt = 0; kt < 16; ++kt) {
      const int kb = kt * 16;
#pragma unroll
      for (int l = 0; l < 2; ++l) {
        int idx = tid + l * 256;
        int m = idx >> 2;
        int kq = (idx & 3) * 4;
        int arow = rowBase + m;
        float4 av = make_float4(0.f, 0.f, 0.f, 0.f);
        if (arow < M) av = *reinterpret_cast<const float4*>(&Ain[arow * 256 + kb + kq]);
        As[kq + 0][m] = av.x; As[kq + 1][m] = av.y;
        As[kq + 2][m] = av.z; As[kq + 3][m] = av.w;
      }
#pragma unroll
      for (int l = 0; l < 2; ++l) {
        int idx = tid + l * 256;
        int k = idx >> 5;
        int nq = (idx & 31) * 4;
        float4 wv = *reinterpret_cast<const float4*>(&Win[(kb + k) * 256 + colBase + nq]);
        *reinterpret_cast<float4*>(&Ws[k][nq]) = wv;
      }
      __syncthreads();
#pragma unroll
      for (int k = 0; k < 16; ++k) {
        float4 a0 = *reinterpret_cast<const float4*>(&As[k][ty * 4]);
        float4 a1 = *reinterpret_cast<const float4*>(&As[k][64 + ty * 4]);
        float4 w0 = *reinterpret_cast<const float4*>(&Ws[k][tx * 4]);
        float4 w1 = *reinterpret_cast<const float4*>(&Ws[k][64 + tx * 4]);
        float ar[2][4] = {{a0.x, a0.y, a0.z, a0.w}, {a1.x, a1.y, a1.z, a1.w}};
        float wr[2][4] = {{w0.x, w0.y, w0.z, w0.w}, {w1.x, w1.y, w1.z, w1.w}};
#pragma unroll
        for (int ri = 0; ri < 2; ++ri)
#pragma unroll
          for (int i = 0; i < 4; ++i)
#pragma unroll
            for (int ci = 0; ci < 2; ++ci)
#pragma unroll
              for (int j = 0; j < 4; ++j)
                acc[ri][ci][i][j] = __fmaf_rn(ar[ri][i], wr[ci][j], acc[ri][ci][i][j]);
      }
      __syncthreads();
    }
  }
  float4 bv0 = *reinterpret_cast<const float4*>(&bias[colBase + tx * 4]);
  float4 bv1 = *reinterpret_cast<const float4*>(&bias[colBase + 64 + tx * 4]);
  float bb[2][4] = {{bv0.x, bv0.y, bv0.z, bv0.w}, {bv1.x, bv1.y, bv1.z, bv1.w}};
#pragma unroll
  for (int ri = 0; ri < 2; ++ri) {
#pragma unroll
    for (int i = 0; i < 4; ++i) {
      int row = rowBase + ri * 64 + ty * 4 + i;
      if (row < M) {
#pragma unroll
        for (int ci = 0; ci < 2; ++ci) {
          float4 o;
          o.x = __fadd_rn(acc[ri][ci][i][0], bb[ci][0]);
          o.y = __fadd_rn(acc[ri][ci][i][1], bb[ci][1]);
          o.z = __fadd_rn(acc[ri][ci][i][2], bb[ci][2]);
          o.w = __fadd_rn(acc[ri][ci][i][3], bb[ci][3]);
          if (RELU) {
            o.x = fmaxf(o.x, 0.f); o.y = fmaxf(o.y, 0.f);
            o.z = fmaxf(o.z, 0.f); o.w = fmaxf(o.w, 0.f);
          }
          *reinterpret_cast<float4*>(&C[row * 256 + colBase + ci * 64 + tx * 4]) = o;
        }
      }
    }
  }
}

// ---------------- CSR gather (segment_sum over incoming edges), fp32 ----------------
__global__ void k_gather(const int* __restrict__ row_start, const int* __restrict__ csr_src,
                         const float* __restrict__ X, float* __restrict__ Cout) {
  int tid = threadIdx.x;
  int r = blockIdx.x * 4 + (tid >> 6);
  int f = (tid & 63) * 4;
  int j0 = row_start[r], j1 = row_start[r + 1];
  float4 acc = make_float4(0.f, 0.f, 0.f, 0.f);
  for (int j = j0; j < j1; ++j) {
    int s = csr_src[j];
    float4 v = *reinterpret_cast<const float4*>(&X[s * 256 + f]);
    acc.x += v.x; acc.y += v.y; acc.z += v.z; acc.w += v.w;
  }
  *reinterpret_cast<float4*>(&Cout[r * 256 + f]) = acc;
}

// ---------------- numpy-faithful f32 router -----------------------------------------
// Consumes the same f32 h as the expert path. Per node: r = single ascending FMA
// chain (sgemm-like) + bias last; LN mean/var with numpy's exact pairwise-8
// bracketing; true divisions everywhere numpy divides; exp via f64 (≈ np.exp u10);
// top-2 with lower-index tie-break.
__global__ __launch_bounds__(64) void k_router_np(
    const float* __restrict__ h, const int* __restrict__ batch,
    const float* __restrict__ gf, const float* __restrict__ lnn,
    const float* __restrict__ rtw1, const float* __restrict__ rtb1,
    const float* __restrict__ lng, const float* __restrict__ lnb,
    const float* __restrict__ rtw2, const float* __restrict__ rtb2,
    const float* __restrict__ centers, float* __restrict__ sw) {
  __shared__ float sh[256];
  __shared__ float sr[128];
  __shared__ float sa[128];
  __shared__ float sb[8];
  const int node = blockIdx.x;   // grid = N exactly
  const int l = threadIdx.x;     // one wave

#pragma unroll
  for (int j = 0; j < 4; ++j) sh[l + 64 * j] = h[node * 256 + l + 64 * j];
  __syncthreads();

  int g = batch[node];
  float gf0 = gf[g * 2 + 0], gf1 = gf[g * 2 + 1], nl = lnn[g];

  float acc0 = 0.f, acc1 = 0.f;
  for (int k = 0; k < 256; ++k) {
    float hv = sh[k];
    acc0 = __fmaf_rn(hv, rtw1[k * RHD + l], acc0);
    acc1 = __fmaf_rn(hv, rtw1[k * RHD + l + 64], acc1);
  }
  acc0 = __fmaf_rn(gf0, rtw1[256 * RHD + l], acc0);
  acc0 = __fmaf_rn(gf1, rtw1[257 * RHD + l], acc0);
  acc1 = __fmaf_rn(gf0, rtw1[256 * RHD + l + 64], acc1);
  acc1 = __fmaf_rn(gf1, rtw1[257 * RHD + l + 64], acc1);
  float r0 = __fadd_rn(acc0, rtb1[l]);
  float r1 = __fadd_rn(acc1, rtb1[l + 64]);
  sr[l] = r0; sr[l + 64] = r1;
  __syncthreads();

  // numpy pairwise-8 mean over 128
  if (l == 0) {
    float a[8];
#pragma unroll
    for (int j = 0; j < 8; ++j) a[j] = sr[j];
    for (int i = 8; i < 128; i += 8)
#pragma unroll
      for (int j = 0; j < 8; ++j) a[j] = __fadd_rn(a[j], sr[i + j]);
    sb[0] = __fdiv_rn(tree8(a), 128.0f);
  }
  __syncthreads();
  float mu = sb[0];
  float d0 = __fsub_rn(r0, mu), d1 = __fsub_rn(r1, mu);
  sr[l] = __fmul_rn(d0, d0);
  sr[l + 64] = __fmul_rn(d1, d1);
  __syncthreads();
  if (l == 0) {
    float a[8];
#pragma unroll
    for (int j = 0; j < 8; ++j) a[j] = sr[j];
    for (int i = 8; i < 128; i += 8)
#pragma unroll
      for (int j = 0; j < 8; ++j) a[j] = __fadd_rn(a[j], sr[i + j]);
    sb[1] = __fdiv_rn(tree8(a), 128.0f);
  }
  __syncthreads();
  float var = sb[1];
  float inv = __fdiv_rn(1.0f, sqrtf(__fadd_rn(var, 1e-5f)));   // lax.rsqrt -> 1/np.sqrt
  float y0 = __fadd_rn(__fmul_rn(__fmul_rn(d0, inv), lng[l]), lnb[l]);
  float y1 = __fadd_rn(__fmul_rn(__fmul_rn(d1, inv), lng[l + 64]), lnb[l + 64]);
  sa[l] = fmaxf(y0, 0.f);
  sa[l + 64] = fmaxf(y1, 0.f);
  __syncthreads();

  // learned logits: single ascending FMA chain over 128 per expert, bias last
  if (l < 4) {
    float acc = 0.f;
    for (int k = 0; k < 128; ++k) acc = __fmaf_rn(sa[k], rtw2[k * 4 + l], acc);
    float lrn = __fadd_rn(acc, rtb2[l]);
    float dd = __fsub_rn(nl, centers[l]);
    float pr = -__fmul_rn(dd, dd);                              // /1.0 exact
    sb[4 + l] = __fadd_rn(__fmul_rn(0.65f, lrn), __fmul_rn(0.35f, pr));
  }
  __syncthreads();

  if (l == 0) {
    float lg[4] = {sb[4], sb[5], sb[6], sb[7]};
    float mx = fmaxf(fmaxf(lg[0], lg[1]), fmaxf(lg[2], lg[3]));
    float e[4];
#pragma unroll
    for (int c = 0; c < 4; ++c)
      e[c] = (float)exp((double)__fsub_rn(lg[c], mx));          // np.exp f32 ≈ c.r.
    float S = __fadd_rn(__fadd_rn(__fadd_rn(e[0], e[1]), e[2]), e[3]);  // np seq n=4
    float p[4];
#pragma unroll
    for (int c = 0; c < 4; ++c) p[c] = __fdiv_rn(e[c], S);      // softmax divides
    int i1 = 0;
#pragma unroll
    for (int c = 1; c < 4; ++c) if (p[c] > p[i1]) i1 = c;       // ties: lower index
    int i2 = -1;
#pragma unroll
    for (int c = 0; c < 4; ++c) {
      if (c == i1) continue;
      if (i2 < 0 || p[c] > p[i2]) i2 = c;
    }
    float den = __fadd_rn(__fadd_rn(p[i1], p[i2]), 1e-8f);
    float swv[4] = {0.f, 0.f, 0.f, 0.f};
    swv[i1] = __fdiv_rn(p[i1], den);                            // topv / (sum+1e-8)
    swv[i2] = __fdiv_rn(p[i2], den);
    *reinterpret_cast<float4*>(&sw[node * 4]) =
        make_float4(swv[0], swv[1], swv[2], swv[3]);
  }
}

// ---------------- output head: out (+)= sw[:,e] * (A2@wro + bro + X2@wto), fp32 -----
template <bool ACC>
__global__ void k_out(const float* __restrict__ A2, const float* __restrict__ X2,
                      const float* __restrict__ wro, const float* __restrict__ bro,
                      const float* __restrict__ wto, const float* __restrict__ sw,
                      float* __restrict__ out, int e) {
  int tid = threadIdx.x;
  int r = blockIdx.x * 4 + (tid >> 6);
  int lane = tid & 63;
  int k0 = lane * 4;
  float wr_[24], wt_[24];
#pragma unroll
  for (int q = 0; q < 6; ++q) {
    float4 a = *reinterpret_cast<const float4*>(&wro[k0 * 6 + q * 4]);
    wr_[q * 4 + 0] = a.x; wr_[q * 4 + 1] = a.y; wr_[q * 4 + 2] = a.z; wr_[q * 4 + 3] = a.w;
    float4 b = *reinterpret_cast<const float4*>(&wto[k0 * 6 + q * 4]);
    wt_[q * 4 + 0] = b.x; wt_[q * 4 + 1] = b.y; wt_[q * 4 + 2] = b.z; wt_[q * 4 + 3] = b.w;
  }
  float4 av4 = *reinterpret_cast<const float4*>(&A2[r * 256 + k0]);
  float4 xv4 = *reinterpret_cast<const float4*>(&X2[r * 256 + k0]);
  float av[4] = {av4.x, av4.y, av4.z, av4.w};
  float xv[4] = {xv4.x, xv4.y, xv4.z, xv4.w};
  float p[6] = {0.f, 0.f, 0.f, 0.f, 0.f, 0.f};
#pragma unroll
  for (int jj = 0; jj < 4; ++jj)
#pragma unroll
    for (int c = 0; c < 6; ++c)
      p[c] += av[jj] * wr_[jj * 6 + c] + xv[jj] * wt_[jj * 6 + c];
#pragma unroll
  for (int off = 32; off > 0; off >>= 1)
#pragma unroll
    for (int c = 0; c < 6; ++c) p[c] += __shfl_down(p[c], off, 64);
  if (lane == 0) {
    float s = sw[r * 4 + e];
#pragma unroll
    for (int c = 0; c < 6; ++c) {
      float v = s * (p[c] + bro[c]);
      if (ACC) out[r * 6 + c] += v;
      else out[r * 6 + c] = v;
    }
  }
}

// ---------------- launch ----------------
extern "C" void kernel_launch(void* const* d_in, const int* in_sizes, int n_in,
                              void* d_out, int out_size, void* d_ws, size_t ws_size,
                              hipStream_t stream) {
  const float* x        = (const float*)d_in[0];
  const int*   edge     = (const int*)d_in[1];
  const int*   batch    = (const int*)d_in[2];
  const float* enc_w1   = (const float*)d_in[4];
  const float* enc_b1   = (const float*)d_in[5];
  const float* enc_w2   = (const float*)d_in[6];
  const float* enc_b2   = (const float*)d_in[7];
  const float* rt_w1    = (const float*)d_in[8];
  const float* rt_b1    = (const float*)d_in[9];
  const float* ln_g     = (const float*)d_in[10];
  const float* ln_b     = (const float*)d_in[11];
  const float* rt_w2    = (const float*)d_in[12];
  const float* rt_b2    = (const float*)d_in[13];
  const float* centers  = (const float*)d_in[14];
  const float* w_rel    = (const float*)d_in[15];
  const float* b_rel    = (const float*)d_in[16];
  const float* w_root   = (const float*)d_in[17];
  const float* w_relo   = (const float*)d_in[18];
  const float* b_relo   = (const float*)d_in[19];
  const float* w_rooto  = (const float*)d_in[20];
  float* out = (float*)d_out;

  char* wsp = (char*)d_ws;
  auto alloc = [&](size_t bytes) -> char* {
    char* p = wsp;
    wsp += (bytes + 255) & ~(size_t)255;
    return p;
  };
  // fp32 activations, 4 x 51.2MB (proven to fit in r5/r6)
  const size_t actB = (size_t)N_NODES * 256 * sizeof(float);
  float* h   = (float*)alloc(actB);
  float* X1  = (float*)alloc(actB);   // enc t, later xe1
  float* A1  = (float*)alloc(actB);   // agg / A1 / A2 (triple-reused)
  float* X2  = (float*)alloc(actB);
  float* swp = (float*)alloc((size_t)N_NODES * 4 * sizeof(float));
  int*   n_cnt = (int*)alloc(NG * sizeof(int));
  int*   e_cnt = (int*)alloc(NG * sizeof(int));
  float* gfbuf = (float*)alloc(NG * 2 * sizeof(float));
  float* lnn   = (float*)alloc(NG * sizeof(float));
  int* deg       = (int*)alloc((size_t)N_NODES * sizeof(int));
  int* row_start = (int*)alloc((size_t)(N_NODES + 1) * sizeof(int));
  int* cursor    = (int*)alloc((size_t)N_NODES * sizeof(int));
  int* csr_src   = (int*)alloc((size_t)NUM_EDGES * sizeof(int));

  // graph stats + CSR build
  k_zero<<<(N_NODES + 255) / 256, 256, 0, stream>>>(deg, n_cnt, e_cnt);
  k_count_nodes<<<(N_NODES + 255) / 256, 256, 0, stream>>>(batch, n_cnt);
  k_count_edges<<<(NUM_EDGES + 255) / 256, 256, 0, stream>>>(edge, batch, e_cnt, deg);
  k_graph_stats<<<1, 64, 0, stream>>>(n_cnt, e_cnt, gfbuf, lnn);
  k_scan<<<1, 1024, 0, stream>>>(deg, row_start, cursor);
  k_fill<<<(NUM_EDGES + 255) / 256, 256, 0, stream>>>(edge, cursor, csr_src);

  // encoder (fp32)
  k_enc1<<<(N_NODES + 15) / 16, 256, 0, stream>>>(x, enc_w1, enc_b1, X1);
  dim3 ggrid((N_NODES + 127) / 128, 2);
  k_gemm<false, false><<<ggrid, 256, 0, stream>>>(X1, enc_w2, nullptr, nullptr, enc_b2, h, N_NODES);

  // numpy-faithful f32 router
  k_router_np<<<N_NODES, 64, 0, stream>>>(
      h, batch, gfbuf, lnn, rt_w1, rt_b1, ln_g, ln_b, rt_w2, rt_b2, centers, swp);

  // experts (fp32; agg recomputed into A1 each expert to fit workspace)
  for (int e = 0; e < NEXP; ++e) {
    const float* wr0 = w_rel  + (size_t)(e * 2 + 0) * 256 * 256;
    const float* wr1 = w_rel  + (size_t)(e * 2 + 1) * 256 * 256;
    const float* wo0 = w_root + (size_t)(e * 2 + 0) * 256 * 256;
    const float* wo1 = w_root + (size_t)(e * 2 + 1) * 256 * 256;
    const float* br0 = b_rel + (size_t)(e * 2 + 0) * 256;
    const float* br1 = b_rel + (size_t)(e * 2 + 1) * 256;
    k_gather<<<N_NODES / 4, 256, 0, stream>>>(row_start, csr_src, h, A1);     // agg_h
    k_gemm<true, true><<<ggrid, 256, 0, stream>>>(A1, wr0, h, wo0, br0, X1, N_NODES);
    k_gather<<<N_NODES / 4, 256, 0, stream>>>(row_start, csr_src, X1, A1);    // A1
    k_gemm<true, true><<<ggrid, 256, 0, stream>>>(A1, wr1, X1, wo1, br1, X2, N_NODES);
    k_gather<<<N_NODES / 4, 256, 0, stream>>>(row_start, csr_src, X2, A1);    // A2
    const float* wro = w_relo  + (size_t)e * 256 * OUTD;
    const float* bro = b_relo  + (size_t)e * OUTD;
    const float* wto = w_rooto + (size_t)e * 256 * OUTD;
    if (e == 0)
      k_out<false><<<N_NODES / 4, 256, 0, stream>>>(A1, X2, wro, bro, wto, swp, out, e);
    else
      k_out<true><<<N_NODES / 4, 256, 0, stream>>>(A1, X2, wro, bro, wto, swp, out, e);
  }
}

// Round 8
// 2387.661 us; speedup vs baseline: 1.5159x; 1.5159x over previous
//
#include <hip/hip_runtime.h>
#include <math.h>

#define N_NODES 50000
#define NUM_EDGES 800000
#define NG 8
#define HID 256
#define RHD 128
#define NEXP 4
#define OUTD 6

typedef unsigned short bf16_t;
using f32x4  = __attribute__((ext_vector_type(4))) float;
using bf16x8 = __attribute__((ext_vector_type(8))) short;

__device__ __forceinline__ unsigned short f2bf(float f) {
  union { float f; unsigned int i; } v; v.f = f;
  unsigned int x = v.i;
  unsigned int r = x + 0x7fffu + ((x >> 16) & 1u);  // RNE
  return (unsigned short)(r >> 16);
}

// ---------------- zero init (graph-capture-safe) ----------------
__global__ void k_zero(int* __restrict__ deg, int* __restrict__ n_cnt,
                       int* __restrict__ e_cnt) {
  int i = blockIdx.x * blockDim.x + threadIdx.x;
  if (i < N_NODES) deg[i] = 0;
  if (i < NG) { n_cnt[i] = 0; e_cnt[i] = 0; }
}

// ---------------- graph stats ----------------
__global__ void k_count_nodes(const int* __restrict__ batch, int* __restrict__ n_cnt) {
  __shared__ int hist[NG];
  int t = threadIdx.x;
  if (t < NG) hist[t] = 0;
  __syncthreads();
  int i = blockIdx.x * blockDim.x + t;
  if (i < N_NODES) atomicAdd(&hist[batch[i]], 1);
  __syncthreads();
  if (t < NG && hist[t]) atomicAdd(&n_cnt[t], hist[t]);
}

__global__ void k_count_edges(const int* __restrict__ edge, const int* __restrict__ batch,
                              int* __restrict__ e_cnt, int* __restrict__ deg) {
  __shared__ int hist[NG];
  int t = threadIdx.x;
  if (t < NG) hist[t] = 0;
  __syncthreads();
  int i = blockIdx.x * blockDim.x + t;
  if (i < NUM_EDGES) {
    int s = edge[i];
    int d = edge[NUM_EDGES + i];
    atomicAdd(&hist[batch[s]], 1);
    atomicAdd(&deg[d], 1);
  }
  __syncthreads();
  if (t < NG && hist[t]) atomicAdd(&e_cnt[t], hist[t]);
}

// numpy-faithful f32 stats (r7, do not touch: razor-sensitive)
__device__ __forceinline__ float tree8(const float* v) {
  float s01 = __fadd_rn(v[0], v[1]);
  float s23 = __fadd_rn(v[2], v[3]);
  float s45 = __fadd_rn(v[4], v[5]);
  float s67 = __fadd_rn(v[6], v[7]);
  return __fadd_rn(__fadd_rn(s01, s23), __fadd_rn(s45, s67));
}

__global__ void k_graph_stats(const int* __restrict__ n_cnt, const int* __restrict__ e_cnt,
                              float* __restrict__ gf, float* __restrict__ lnn) {
  if (threadIdx.x != 0 || blockIdx.x != 0) return;
  float logn[NG], loge[NG];
  for (int g = 0; g < NG; ++g) {
    float nf = fmaxf((float)n_cnt[g], 1.0f);
    logn[g] = (float)log((double)nf);
    float ef = fmaxf((float)e_cnt[g], 0.0f);
    loge[g] = (float)log1p((double)ef);
  }
  float m0 = __fdiv_rn(tree8(logn), 8.0f);
  float m1 = __fdiv_rn(tree8(loge), 8.0f);
  float sq0[NG], sq1[NG];
  float mn = 3.0e38f, mx = -3.0e38f;
  for (int g = 0; g < NG; ++g) {
    float d0 = __fsub_rn(logn[g], m0);
    float d1 = __fsub_rn(loge[g], m1);
    sq0[g] = __fmul_rn(d0, d0);
    sq1[g] = __fmul_rn(d1, d1);
    mn = fminf(mn, logn[g]); mx = fmaxf(mx, logn[g]);
  }
  float s0 = __fadd_rn(sqrtf(__fdiv_rn(tree8(sq0), 8.0f)), 1e-6f);
  float s1 = __fadd_rn(sqrtf(__fdiv_rn(tree8(sq1), 8.0f)), 1e-6f);
  float denom = __fadd_rn(__fsub_rn(mx, mn), 1e-6f);
  for (int g = 0; g < NG; ++g) {
    gf[g * 2 + 0] = __fdiv_rn(__fsub_rn(logn[g], m0), s0);
    gf[g * 2 + 1] = __fdiv_rn(__fsub_rn(loge[g], m1), s1);
    lnn[g] = __fdiv_rn(__fsub_rn(logn[g], mn), denom);
  }
}

// ---------------- CSR build ----------------
__global__ void k_scan(const int* __restrict__ deg, int* __restrict__ row_start,
                       int* __restrict__ cursor) {
  __shared__ int temp[1024];
  int tid = threadIdx.x;
  int carry = 0;
  for (int base = 0; base < N_NODES; base += 1024) {
    int i = base + tid;
    int v = (i < N_NODES) ? deg[i] : 0;
    temp[tid] = v;
    __syncthreads();
    for (int off = 1; off < 1024; off <<= 1) {
      int t = (tid >= off) ? temp[tid - off] : 0;
      __syncthreads();
      temp[tid] += t;
      __syncthreads();
    }
    int incl = temp[tid];
    if (i < N_NODES) {
      int e = carry + incl - v;
      row_start[i] = e;
      cursor[i] = e;
    }
    carry += temp[1023];
    __syncthreads();
  }
  if (tid == 0) row_start[N_NODES] = carry;
}

__global__ void k_fill(const int* __restrict__ edge, int* __restrict__ cursor,
                       int* __restrict__ csr_src) {
  int i = blockIdx.x * blockDim.x + threadIdx.x;
  if (i < NUM_EDGES) {
    int d = edge[NUM_EDGES + i];
    int p = atomicAdd(&cursor[d], 1);
    csr_src[p] = edge[i];
  }
}

// ---------------- encoder layer 1 (r7, untouched: feeds router-sensitive h) --------
__global__ void k_enc1(const float* __restrict__ x, const float* __restrict__ w1,
                       const float* __restrict__ b1, float* __restrict__ t) {
  __shared__ float W[6 * 256];
  __shared__ float xs[16][6];
  int tid = threadIdx.x;
  for (int i = tid; i < 6 * 256; i += 256) W[i] = w1[i];
  int base = blockIdx.x * 16;
  if (tid < 96) {
    int n = tid / 6, k = tid % 6;
    int node = base + n;
    xs[n][k] = (node < N_NODES) ? x[node * 16 + 4 + k] : 0.f;
  }
  __syncthreads();
  float b = b1[tid];
  for (int n = 0; n < 16; ++n) {
    int node = base + n;
    if (node >= N_NODES) break;
    float acc = 0.f;
#pragma unroll
    for (int k = 0; k < 6; ++k) acc = __fmaf_rn(xs[n][k], W[k * 256 + tid], acc);
    t[node * 256 + tid] = fmaxf(__fadd_rn(acc, b), 0.f);
  }
}

// ---------------- fp32 SIMT GEMM (kept ONLY for the encoder h GEMM: bit-stable) -----
template <bool RELU, bool HASB>
__global__ __launch_bounds__(256, 2) void k_gemm(
    const float* __restrict__ A, const float* __restrict__ W0,
    const float* __restrict__ B, const float* __restrict__ W1,
    const float* __restrict__ bias, float* __restrict__ C, int M) {
  __shared__ float As[16][132];
  __shared__ float Ws[16][128];
  const int tid = threadIdx.x;
  const int tx = tid & 15;
  const int ty = tid >> 4;
  const int rowBase = blockIdx.x * 128;
  const int colBase = blockIdx.y * 128;

  float acc[2][2][4][4];
#pragma unroll
  for (int a = 0; a < 2; ++a)
#pragma unroll
    for (int b = 0; b < 2; ++b)
#pragma unroll
      for (int i = 0; i < 4; ++i)
#pragma unroll
        for (int j = 0; j < 4; ++j) acc[a][b][i][j] = 0.f;

  const int NPHASE = HASB ? 2 : 1;
  for (int phase = 0; phase < NPHASE; ++phase) {
    const float* __restrict__ Ain = phase ? B : A;
    const float* __restrict__ Win = phase ? W1 : W0;
    for (int kt = 0; kt < 16; ++kt) {
      const int kb = kt * 16;
#pragma unroll
      for (int l = 0; l < 2; ++l) {
        int idx = tid + l * 256;
        int m = idx >> 2;
        int kq = (idx & 3) * 4;
        int arow = rowBase + m;
        float4 av = make_float4(0.f, 0.f, 0.f, 0.f);
        if (arow < M) av = *reinterpret_cast<const float4*>(&Ain[arow * 256 + kb + kq]);
        As[kq + 0][m] = av.x; As[kq + 1][m] = av.y;
        As[kq + 2][m] = av.z; As[kq + 3][m] = av.w;
      }
#pragma unroll
      for (int l = 0; l < 2; ++l) {
        int idx = tid + l * 256;
        int k = idx >> 5;
        int nq = (idx & 31) * 4;
        float4 wv = *reinterpret_cast<const float4*>(&Win[(kb + k) * 256 + colBase + nq]);
        *reinterpret_cast<float4*>(&Ws[k][nq]) = wv;
      }
      __syncthreads();
#pragma unroll
      for (int k = 0; k < 16; ++k) {
        float4 a0 = *reinterpret_cast<const float4*>(&As[k][ty * 4]);
        float4 a1 = *reinterpret_cast<const float4*>(&As[k][64 + ty * 4]);
        float4 w0 = *reinterpret_cast<const float4*>(&Ws[k][tx * 4]);
        float4 w1 = *reinterpret_cast<const float4*>(&Ws[k][64 + tx * 4]);
        float ar[2][4] = {{a0.x, a0.y, a0.z, a0.w}, {a1.x, a1.y, a1.z, a1.w}};
        float wr[2][4] = {{w0.x, w0.y, w0.z, w0.w}, {w1.x, w1.y, w1.z, w1.w}};
#pragma unroll
        for (int ri = 0; ri < 2; ++ri)
#pragma unroll
          for (int i = 0; i < 4; ++i)
#pragma unroll
            for (int ci = 0; ci < 2; ++ci)
#pragma unroll
              for (int j = 0; j < 4; ++j)
                acc[ri][ci][i][j] = __fmaf_rn(ar[ri][i], wr[ci][j], acc[ri][ci][i][j]);
      }
      __syncthreads();
    }
  }
  float4 bv0 = *reinterpret_cast<const float4*>(&bias[colBase + tx * 4]);
  float4 bv1 = *reinterpret_cast<const float4*>(&bias[colBase + 64 + tx * 4]);
  float bb[2][4] = {{bv0.x, bv0.y, bv0.z, bv0.w}, {bv1.x, bv1.y, bv1.z, bv1.w}};
#pragma unroll
  for (int ri = 0; ri < 2; ++ri) {
#pragma unroll
    for (int i = 0; i < 4; ++i) {
      int row = rowBase + ri * 64 + ty * 4 + i;
      if (row < M) {
#pragma unroll
        for (int ci = 0; ci < 2; ++ci) {
          float4 o;
          o.x = __fadd_rn(acc[ri][ci][i][0], bb[ci][0]);
          o.y = __fadd_rn(acc[ri][ci][i][1], bb[ci][1]);
          o.z = __fadd_rn(acc[ri][ci][i][2], bb[ci][2]);
          o.w = __fadd_rn(acc[ri][ci][i][3], bb[ci][3]);
          if (RELU) {
            o.x = fmaxf(o.x, 0.f); o.y = fmaxf(o.y, 0.f);
            o.z = fmaxf(o.z, 0.f); o.w = fmaxf(o.w, 0.f);
          }
          *reinterpret_cast<float4*>(&C[row * 256 + colBase + ci * 64 + tx * 4]) = o;
        }
      }
    }
  }
}

// ---------------- MFMA bf16 GEMM for EXPERT layers ---------------------------------
// C = relu(A@W0 + B@W1 + bias). A,B,W f32 in memory; bf16-converted in LDS staging;
// f32 accumulate (MFMA); f32 output. 128x128 tile, 4 waves x (4x4) 16x16x32 frags.
// Verified layouts: A-frag A[m=lane&15][k=quad*8+j]; C/D col=lane&15,row=quad*4+reg.
#define LDS_STRIDE 40   // 32 bf16 + 8 pad: 80B rows keep 16B alignment, <=2-way banks
__global__ __launch_bounds__(256) void k_gemm_mfma(
    const float* __restrict__ A, const float* __restrict__ W0,
    const float* __restrict__ B, const float* __restrict__ W1,
    const float* __restrict__ bias, float* __restrict__ C, int M) {
  __shared__ bf16_t As[128 * LDS_STRIDE];
  __shared__ bf16_t Ws[128 * LDS_STRIDE];
  const int tid = threadIdx.x;
  const int lane = tid & 63;
  const int wave = tid >> 6;
  const int lm = lane & 15;
  const int quad = lane >> 4;
  const int wm = (wave >> 1) * 64;   // wave row offset in tile
  const int wn = (wave & 1) * 64;    // wave col offset
  const int rowBase = blockIdx.x * 128;
  const int colBase = blockIdx.y * 128;

  f32x4 acc[4][4];
#pragma unroll
  for (int i = 0; i < 4; ++i)
#pragma unroll
    for (int j = 0; j < 4; ++j) acc[i][j] = (f32x4){0.f, 0.f, 0.f, 0.f};

  for (int phase = 0; phase < 2; ++phase) {
    const float* __restrict__ Ain = phase ? B : A;
    const float* __restrict__ Win = phase ? W1 : W0;
    for (int kt = 0; kt < 8; ++kt) {          // K = 256 per phase, BK = 32
      const int kb = kt * 32;
      // stage A: 128 rows x 32 k (f32 -> bf16), layout As[m][k]
#pragma unroll
      for (int q = 0; q < 4; ++q) {
        int idx = tid * 4 + q;                // 0..1023 float4s
        int row = idx >> 3;
        int k4 = (idx & 7) * 4;
        int arow = rowBase + row;
        float4 v = make_float4(0.f, 0.f, 0.f, 0.f);
        if (arow < M) v = *reinterpret_cast<const float4*>(&Ain[arow * 256 + kb + k4]);
        ushort4 o = make_ushort4(f2bf(v.x), f2bf(v.y), f2bf(v.z), f2bf(v.w));
        *reinterpret_cast<ushort4*>(&As[row * LDS_STRIDE + k4]) = o;
      }
      // stage W: 32 k x 128 n, transposed to Ws[n][k] (f32 -> bf16)
#pragma unroll
      for (int q = 0; q < 4; ++q) {
        int idx = tid * 4 + q;
        int kk = idx >> 5;
        int n4 = (idx & 31) * 4;
        float4 w = *reinterpret_cast<const float4*>(&Win[(kb + kk) * 256 + colBase + n4]);
        Ws[(n4 + 0) * LDS_STRIDE + kk] = f2bf(w.x);
        Ws[(n4 + 1) * LDS_STRIDE + kk] = f2bf(w.y);
        Ws[(n4 + 2) * LDS_STRIDE + kk] = f2bf(w.z);
        Ws[(n4 + 3) * LDS_STRIDE + kk] = f2bf(w.w);
      }
      __syncthreads();
      bf16x8 af[4], bf[4];
#pragma unroll
      for (int i = 0; i < 4; ++i)
        af[i] = *reinterpret_cast<const bf16x8*>(&As[(wm + i * 16 + lm) * LDS_STRIDE + quad * 8]);
#pragma unroll
      for (int j = 0; j < 4; ++j)
        bf[j] = *reinterpret_cast<const bf16x8*>(&Ws[(wn + j * 16 + lm) * LDS_STRIDE + quad * 8]);
#pragma unroll
      for (int i = 0; i < 4; ++i)
#pragma unroll
        for (int j = 0; j < 4; ++j)
          acc[i][j] = __builtin_amdgcn_mfma_f32_16x16x32_bf16(af[i], bf[j], acc[i][j], 0, 0, 0);
      __syncthreads();
    }
  }
  // epilogue: D col = lane&15, row = quad*4 + reg
#pragma unroll
  for (int i = 0; i < 4; ++i) {
#pragma unroll
    for (int r = 0; r < 4; ++r) {
      int row = rowBase + wm + i * 16 + quad * 4 + r;
      if (row < M) {
#pragma unroll
        for (int j = 0; j < 4; ++j) {
          int col = colBase + wn + j * 16 + lm;
          float v = acc[i][j][r] + bias[col];
          C[row * 256 + col] = fmaxf(v, 0.f);
        }
      }
    }
  }
}

// ---------------- CSR gather (segment_sum over incoming edges), fp32 ----------------
__global__ void k_gather(const int* __restrict__ row_start, const int* __restrict__ csr_src,
                         const float* __restrict__ X, float* __restrict__ Cout) {
  int tid = threadIdx.x;
  int r = blockIdx.x * 4 + (tid >> 6);
  int f = (tid & 63) * 4;
  int j0 = row_start[r], j1 = row_start[r + 1];
  float4 acc = make_float4(0.f, 0.f, 0.f, 0.f);
  for (int j = j0; j < j1; ++j) {
    int s = csr_src[j];
    float4 v = *reinterpret_cast<const float4*>(&X[s * 256 + f]);
    acc.x += v.x; acc.y += v.y; acc.z += v.z; acc.w += v.w;
  }
  *reinterpret_cast<float4*>(&Cout[r * 256 + f]) = acc;
}

// ---------------- numpy-faithful f32 router (r7, untouched) ------------------------
__global__ __launch_bounds__(64) void k_router_np(
    const float* __restrict__ h, const int* __restrict__ batch,
    const float* __restrict__ gf, const float* __restrict__ lnn,
    const float* __restrict__ rtw1, const float* __restrict__ rtb1,
    const float* __restrict__ lng, const float* __restrict__ lnb,
    const float* __restrict__ rtw2, const float* __restrict__ rtb2,
    const float* __restrict__ centers, float* __restrict__ sw) {
  __shared__ float sh[256];
  __shared__ float sr[128];
  __shared__ float sa[128];
  __shared__ float sb[8];
  const int node = blockIdx.x;
  const int l = threadIdx.x;

#pragma unroll
  for (int j = 0; j < 4; ++j) sh[l + 64 * j] = h[node * 256 + l + 64 * j];
  __syncthreads();

  int g = batch[node];
  float gf0 = gf[g * 2 + 0], gf1 = gf[g * 2 + 1], nl = lnn[g];

  float acc0 = 0.f, acc1 = 0.f;
  for (int k = 0; k < 256; ++k) {
    float hv = sh[k];
    acc0 = __fmaf_rn(hv, rtw1[k * RHD + l], acc0);
    acc1 = __fmaf_rn(hv, rtw1[k * RHD + l + 64], acc1);
  }
  acc0 = __fmaf_rn(gf0, rtw1[256 * RHD + l], acc0);
  acc0 = __fmaf_rn(gf1, rtw1[257 * RHD + l], acc0);
  acc1 = __fmaf_rn(gf0, rtw1[256 * RHD + l + 64], acc1);
  acc1 = __fmaf_rn(gf1, rtw1[257 * RHD + l + 64], acc1);
  float r0 = __fadd_rn(acc0, rtb1[l]);
  float r1 = __fadd_rn(acc1, rtb1[l + 64]);
  sr[l] = r0; sr[l + 64] = r1;
  __syncthreads();

  if (l == 0) {
    float a[8];
#pragma unroll
    for (int j = 0; j < 8; ++j) a[j] = sr[j];
    for (int i = 8; i < 128; i += 8)
#pragma unroll
      for (int j = 0; j < 8; ++j) a[j] = __fadd_rn(a[j], sr[i + j]);
    sb[0] = __fdiv_rn(tree8(a), 128.0f);
  }
  __syncthreads();
  float mu = sb[0];
  float d0 = __fsub_rn(r0, mu), d1 = __fsub_rn(r1, mu);
  sr[l] = __fmul_rn(d0, d0);
  sr[l + 64] = __fmul_rn(d1, d1);
  __syncthreads();
  if (l == 0) {
    float a[8];
#pragma unroll
    for (int j = 0; j < 8; ++j) a[j] = sr[j];
    for (int i = 8; i < 128; i += 8)
#pragma unroll
      for (int j = 0; j < 8; ++j) a[j] = __fadd_rn(a[j], sr[i + j]);
    sb[1] = __fdiv_rn(tree8(a), 128.0f);
  }
  __syncthreads();
  float var = sb[1];
  float inv = __fdiv_rn(1.0f, sqrtf(__fadd_rn(var, 1e-5f)));
  float y0 = __fadd_rn(__fmul_rn(__fmul_rn(d0, inv), lng[l]), lnb[l]);
  float y1 = __fadd_rn(__fmul_rn(__fmul_rn(d1, inv), lng[l + 64]), lnb[l + 64]);
  sa[l] = fmaxf(y0, 0.f);
  sa[l + 64] = fmaxf(y1, 0.f);
  __syncthreads();

  if (l < 4) {
    float acc = 0.f;
    for (int k = 0; k < 128; ++k) acc = __fmaf_rn(sa[k], rtw2[k * 4 + l], acc);
    float lrn = __fadd_rn(acc, rtb2[l]);
    float dd = __fsub_rn(nl, centers[l]);
    float pr = -__fmul_rn(dd, dd);
    sb[4 + l] = __fadd_rn(__fmul_rn(0.65f, lrn), __fmul_rn(0.35f, pr));
  }
  __syncthreads();

  if (l == 0) {
    float lg[4] = {sb[4], sb[5], sb[6], sb[7]};
    float mx = fmaxf(fmaxf(lg[0], lg[1]), fmaxf(lg[2], lg[3]));
    float e[4];
#pragma unroll
    for (int c = 0; c < 4; ++c)
      e[c] = (float)exp((double)__fsub_rn(lg[c], mx));
    float S = __fadd_rn(__fadd_rn(__fadd_rn(e[0], e[1]), e[2]), e[3]);
    float p[4];
#pragma unroll
    for (int c = 0; c < 4; ++c) p[c] = __fdiv_rn(e[c], S);
    int i1 = 0;
#pragma unroll
    for (int c = 1; c < 4; ++c) if (p[c] > p[i1]) i1 = c;
    int i2 = -1;
#pragma unroll
    for (int c = 0; c < 4; ++c) {
      if (c == i1) continue;
      if (i2 < 0 || p[c] > p[i2]) i2 = c;
    }
    float den = __fadd_rn(__fadd_rn(p[i1], p[i2]), 1e-8f);
    float swv[4] = {0.f, 0.f, 0.f, 0.f};
    swv[i1] = __fdiv_rn(p[i1], den);
    swv[i2] = __fdiv_rn(p[i2], den);
    *reinterpret_cast<float4*>(&sw[node * 4]) =
        make_float4(swv[0], swv[1], swv[2], swv[3]);
  }
}

// ---------------- output head ------------------------------------------------------
template <bool ACC>
__global__ void k_out(const float* __restrict__ A2, const float* __restrict__ X2,
                      const float* __restrict__ wro, const float* __restrict__ bro,
                      const float* __restrict__ wto, const float* __restrict__ sw,
                      float* __restrict__ out, int e) {
  int tid = threadIdx.x;
  int r = blockIdx.x * 4 + (tid >> 6);
  int lane = tid & 63;
  int k0 = lane * 4;
  float wr_[24], wt_[24];
#pragma unroll
  for (int q = 0; q < 6; ++q) {
    float4 a = *reinterpret_cast<const float4*>(&wro[k0 * 6 + q * 4]);
    wr_[q * 4 + 0] = a.x; wr_[q * 4 + 1] = a.y; wr_[q * 4 + 2] = a.z; wr_[q * 4 + 3] = a.w;
    float4 b = *reinterpret_cast<const float4*>(&wto[k0 * 6 + q * 4]);
    wt_[q * 4 + 0] = b.x; wt_[q * 4 + 1] = b.y; wt_[q * 4 + 2] = b.z; wt_[q * 4 + 3] = b.w;
  }
  float4 av4 = *reinterpret_cast<const float4*>(&A2[r * 256 + k0]);
  float4 xv4 = *reinterpret_cast<const float4*>(&X2[r * 256 + k0]);
  float av[4] = {av4.x, av4.y, av4.z, av4.w};
  float xv[4] = {xv4.x, xv4.y, xv4.z, xv4.w};
  float p[6] = {0.f, 0.f, 0.f, 0.f, 0.f, 0.f};
#pragma unroll
  for (int jj = 0; jj < 4; ++jj)
#pragma unroll
    for (int c = 0; c < 6; ++c)
      p[c] += av[jj] * wr_[jj * 6 + c] + xv[jj] * wt_[jj * 6 + c];
#pragma unroll
  for (int off = 32; off > 0; off >>= 1)
#pragma unroll
    for (int c = 0; c < 6; ++c) p[c] += __shfl_down(p[c], off, 64);
  if (lane == 0) {
    float s = sw[r * 4 + e];
#pragma unroll
    for (int c = 0; c < 6; ++c) {
      float v = s * (p[c] + bro[c]);
      if (ACC) out[r * 6 + c] += v;
      else out[r * 6 + c] = v;
    }
  }
}

// ---------------- launch ----------------
extern "C" void kernel_launch(void* const* d_in, const int* in_sizes, int n_in,
                              void* d_out, int out_size, void* d_ws, size_t ws_size,
                              hipStream_t stream) {
  const float* x        = (const float*)d_in[0];
  const int*   edge     = (const int*)d_in[1];
  const int*   batch    = (const int*)d_in[2];
  const float* enc_w1   = (const float*)d_in[4];
  const float* enc_b1   = (const float*)d_in[5];
  const float* enc_w2   = (const float*)d_in[6];
  const float* enc_b2   = (const float*)d_in[7];
  const float* rt_w1    = (const float*)d_in[8];
  const float* rt_b1    = (const float*)d_in[9];
  const float* ln_g     = (const float*)d_in[10];
  const float* ln_b     = (const float*)d_in[11];
  const float* rt_w2    = (const float*)d_in[12];
  const float* rt_b2    = (const float*)d_in[13];
  const float* centers  = (const float*)d_in[14];
  const float* w_rel    = (const float*)d_in[15];
  const float* b_rel    = (const float*)d_in[16];
  const float* w_root   = (const float*)d_in[17];
  const float* w_relo   = (const float*)d_in[18];
  const float* b_relo   = (const float*)d_in[19];
  const float* w_rooto  = (const float*)d_in[20];
  float* out = (float*)d_out;

  char* wsp = (char*)d_ws;
  auto alloc = [&](size_t bytes) -> char* {
    char* p = wsp;
    wsp += (bytes + 255) & ~(size_t)255;
    return p;
  };
  const size_t actB = (size_t)N_NODES * 256 * sizeof(float);
  float* h   = (float*)alloc(actB);
  float* X1  = (float*)alloc(actB);
  float* A1  = (float*)alloc(actB);
  float* X2  = (float*)alloc(actB);
  float* swp = (float*)alloc((size_t)N_NODES * 4 * sizeof(float));
  int*   n_cnt = (int*)alloc(NG * sizeof(int));
  int*   e_cnt = (int*)alloc(NG * sizeof(int));
  float* gfbuf = (float*)alloc(NG * 2 * sizeof(float));
  float* lnn   = (float*)alloc(NG * sizeof(float));
  int* deg       = (int*)alloc((size_t)N_NODES * sizeof(int));
  int* row_start = (int*)alloc((size_t)(N_NODES + 1) * sizeof(int));
  int* cursor    = (int*)alloc((size_t)N_NODES * sizeof(int));
  int* csr_src   = (int*)alloc((size_t)NUM_EDGES * sizeof(int));

  // Optional dedicated agg buffer: gather(h) is loop-invariant; hoist it if the
  // workspace has room (ws_size is constant across calls -> capture-safe branch).
  size_t used = (size_t)(wsp - (char*)d_ws);
  float* AGG = nullptr;
  if (ws_size >= used + actB) AGG = (float*)alloc(actB);

  // graph stats + CSR build
  k_zero<<<(N_NODES + 255) / 256, 256, 0, stream>>>(deg, n_cnt, e_cnt);
  k_count_nodes<<<(N_NODES + 255) / 256, 256, 0, stream>>>(batch, n_cnt);
  k_count_edges<<<(NUM_EDGES + 255) / 256, 256, 0, stream>>>(edge, batch, e_cnt, deg);
  k_graph_stats<<<1, 64, 0, stream>>>(n_cnt, e_cnt, gfbuf, lnn);
  k_scan<<<1, 1024, 0, stream>>>(deg, row_start, cursor);
  k_fill<<<(NUM_EDGES + 255) / 256, 256, 0, stream>>>(edge, cursor, csr_src);

  // encoder (fp32 SIMT, bit-identical to r7 -> h preserved for router)
  k_enc1<<<(N_NODES + 15) / 16, 256, 0, stream>>>(x, enc_w1, enc_b1, X1);
  dim3 ggrid((N_NODES + 127) / 128, 2);
  k_gemm<false, false><<<ggrid, 256, 0, stream>>>(X1, enc_w2, nullptr, nullptr, enc_b2, h, N_NODES);

  // numpy-faithful f32 router (untouched)
  k_router_np<<<N_NODES, 64, 0, stream>>>(
      h, batch, gfbuf, lnn, rt_w1, rt_b1, ln_g, ln_b, rt_w2, rt_b2, centers, swp);

  if (AGG)
    k_gather<<<N_NODES / 4, 256, 0, stream>>>(row_start, csr_src, h, AGG);

  // experts: MFMA bf16 GEMMs (f32 in/out, bf16 multiply operands)
  for (int e = 0; e < NEXP; ++e) {
    const float* wr0 = w_rel  + (size_t)(e * 2 + 0) * 256 * 256;
    const float* wr1 = w_rel  + (size_t)(e * 2 + 1) * 256 * 256;
    const float* wo0 = w_root + (size_t)(e * 2 + 0) * 256 * 256;
    const float* wo1 = w_root + (size_t)(e * 2 + 1) * 256 * 256;
    const float* br0 = b_rel + (size_t)(e * 2 + 0) * 256;
    const float* br1 = b_rel + (size_t)(e * 2 + 1) * 256;
    const float* aggp = AGG;
    if (!AGG) {
      k_gather<<<N_NODES / 4, 256, 0, stream>>>(row_start, csr_src, h, A1);
      aggp = A1;
    }
    k_gemm_mfma<<<ggrid, 256, 0, stream>>>(aggp, wr0, h, wo0, br0, X1, N_NODES);
    k_gather<<<N_NODES / 4, 256, 0, stream>>>(row_start, csr_src, X1, A1);
    k_gemm_mfma<<<ggrid, 256, 0, stream>>>(A1, wr1, X1, wo1, br1, X2, N_NODES);
    k_gather<<<N_NODES / 4, 256, 0, stream>>>(row_start, csr_src, X2, A1);
    const float* wro = w_relo  + (size_t)e * 256 * OUTD;
    const float* bro = b_relo  + (size_t)e * OUTD;
    const float* wto = w_rooto + (size_t)e * 256 * OUTD;
    if (e == 0)
      k_out<false><<<N_NODES / 4, 256, 0, stream>>>(A1, X2, wro, bro, wto, swp, out, e);
    else
      k_out<true><<<N_NODES / 4, 256, 0, stream>>>(A1, X2, wro, bro, wto, swp, out, e);
  }
}

// Round 9
// 1813.573 us; speedup vs baseline: 1.9958x; 1.3166x over previous
//
#include <hip/hip_runtime.h>
#include <math.h>

#define N_NODES 50000
#define M_PAD 50048            // 391 * 128
#define NUM_EDGES 800000
#define NG 8
#define HID 256
#define RHD 128
#define NEXP 4
#define OUTD 6

typedef unsigned short bf16_t;
using f32x4  = __attribute__((ext_vector_type(4))) float;
using bf16x8 = __attribute__((ext_vector_type(8))) short;

__device__ __forceinline__ float bf2f(unsigned short u) {
  union { unsigned int i; float f; } v; v.i = ((unsigned int)u) << 16; return v.f;
}
__device__ __forceinline__ unsigned short f2bf(float f) {
  union { float f; unsigned int i; } v; v.f = f;
  unsigned int x = v.i;
  unsigned int r = x + 0x7fffu + ((x >> 16) & 1u);  // RNE
  return (unsigned short)(r >> 16);
}

// ---------------- zero init (graph-capture-safe) ----------------
__global__ void k_zero(int* __restrict__ deg, int* __restrict__ n_cnt,
                       int* __restrict__ e_cnt) {
  int i = blockIdx.x * blockDim.x + threadIdx.x;
  if (i < N_NODES) deg[i] = 0;
  if (i < NG) { n_cnt[i] = 0; e_cnt[i] = 0; }
}

// ---------------- graph stats ----------------
__global__ void k_count_nodes(const int* __restrict__ batch, int* __restrict__ n_cnt) {
  __shared__ int hist[NG];
  int t = threadIdx.x;
  if (t < NG) hist[t] = 0;
  __syncthreads();
  int i = blockIdx.x * blockDim.x + t;
  if (i < N_NODES) atomicAdd(&hist[batch[i]], 1);
  __syncthreads();
  if (t < NG && hist[t]) atomicAdd(&n_cnt[t], hist[t]);
}

__global__ void k_count_edges(const int* __restrict__ edge, const int* __restrict__ batch,
                              int* __restrict__ e_cnt, int* __restrict__ deg) {
  __shared__ int hist[NG];
  int t = threadIdx.x;
  if (t < NG) hist[t] = 0;
  __syncthreads();
  int i = blockIdx.x * blockDim.x + t;
  if (i < NUM_EDGES) {
    int s = edge[i];
    int d = edge[NUM_EDGES + i];
    atomicAdd(&hist[batch[s]], 1);
    atomicAdd(&deg[d], 1);
  }
  __syncthreads();
  if (t < NG && hist[t]) atomicAdd(&e_cnt[t], hist[t]);
}

// numpy-faithful f32 stats (frozen: razor-sensitive)
__device__ __forceinline__ float tree8(const float* v) {
  float s01 = __fadd_rn(v[0], v[1]);
  float s23 = __fadd_rn(v[2], v[3]);
  float s45 = __fadd_rn(v[4], v[5]);
  float s67 = __fadd_rn(v[6], v[7]);
  return __fadd_rn(__fadd_rn(s01, s23), __fadd_rn(s45, s67));
}

__global__ void k_graph_stats(const int* __restrict__ n_cnt, const int* __restrict__ e_cnt,
                              float* __restrict__ gf, float* __restrict__ lnn) {
  if (threadIdx.x != 0 || blockIdx.x != 0) return;
  float logn[NG], loge[NG];
  for (int g = 0; g < NG; ++g) {
    float nf = fmaxf((float)n_cnt[g], 1.0f);
    logn[g] = (float)log((double)nf);
    float ef = fmaxf((float)e_cnt[g], 0.0f);
    loge[g] = (float)log1p((double)ef);
  }
  float m0 = __fdiv_rn(tree8(logn), 8.0f);
  float m1 = __fdiv_rn(tree8(loge), 8.0f);
  float sq0[NG], sq1[NG];
  float mn = 3.0e38f, mx = -3.0e38f;
  for (int g = 0; g < NG; ++g) {
    float d0 = __fsub_rn(logn[g], m0);
    float d1 = __fsub_rn(loge[g], m1);
    sq0[g] = __fmul_rn(d0, d0);
    sq1[g] = __fmul_rn(d1, d1);
    mn = fminf(mn, logn[g]); mx = fmaxf(mx, logn[g]);
  }
  float s0 = __fadd_rn(sqrtf(__fdiv_rn(tree8(sq0), 8.0f)), 1e-6f);
  float s1 = __fadd_rn(sqrtf(__fdiv_rn(tree8(sq1), 8.0f)), 1e-6f);
  float denom = __fadd_rn(__fsub_rn(mx, mn), 1e-6f);
  for (int g = 0; g < NG; ++g) {
    gf[g * 2 + 0] = __fdiv_rn(__fsub_rn(logn[g], m0), s0);
    gf[g * 2 + 1] = __fdiv_rn(__fsub_rn(loge[g], m1), s1);
    lnn[g] = __fdiv_rn(__fsub_rn(logn[g], mn), denom);
  }
}

// ---------------- CSR build ----------------
__global__ void k_scan(const int* __restrict__ deg, int* __restrict__ row_start,
                       int* __restrict__ cursor) {
  __shared__ int temp[1024];
  int tid = threadIdx.x;
  int carry = 0;
  for (int base = 0; base < N_NODES; base += 1024) {
    int i = base + tid;
    int v = (i < N_NODES) ? deg[i] : 0;
    temp[tid] = v;
    __syncthreads();
    for (int off = 1; off < 1024; off <<= 1) {
      int t = (tid >= off) ? temp[tid - off] : 0;
      __syncthreads();
      temp[tid] += t;
      __syncthreads();
    }
    int incl = temp[tid];
    if (i < N_NODES) {
      int e = carry + incl - v;
      row_start[i] = e;
      cursor[i] = e;
    }
    carry += temp[1023];
    __syncthreads();
  }
  if (tid == 0) row_start[N_NODES] = carry;
}

__global__ void k_fill(const int* __restrict__ edge, int* __restrict__ cursor,
                       int* __restrict__ csr_src) {
  int i = blockIdx.x * blockDim.x + threadIdx.x;
  if (i < NUM_EDGES) {
    int d = edge[NUM_EDGES + i];
    int p = atomicAdd(&cursor[d], 1);
    csr_src[p] = edge[i];
  }
}

// ---------------- encoder layer 1 (frozen: feeds router-sensitive h) ---------------
__global__ void k_enc1(const float* __restrict__ x, const float* __restrict__ w1,
                       const float* __restrict__ b1, float* __restrict__ t) {
  __shared__ float W[6 * 256];
  __shared__ float xs[16][6];
  int tid = threadIdx.x;
  for (int i = tid; i < 6 * 256; i += 256) W[i] = w1[i];
  int base = blockIdx.x * 16;
  if (tid < 96) {
    int n = tid / 6, k = tid % 6;
    int node = base + n;
    xs[n][k] = (node < N_NODES) ? x[node * 16 + 4 + k] : 0.f;
  }
  __syncthreads();
  float b = b1[tid];
  for (int n = 0; n < 16; ++n) {
    int node = base + n;
    if (node >= N_NODES) break;
    float acc = 0.f;
#pragma unroll
    for (int k = 0; k < 6; ++k) acc = __fmaf_rn(xs[n][k], W[k * 256 + tid], acc);
    t[node * 256 + tid] = fmaxf(__fadd_rn(acc, b), 0.f);
  }
}

// ---------------- fp32 SIMT GEMM (frozen, encoder h GEMM only) ----------------------
template <bool RELU, bool HASB>
__global__ __launch_bounds__(256, 2) void k_gemm(
    const float* __restrict__ A, const float* __restrict__ W0,
    const float* __restrict__ B, const float* __restrict__ W1,
    const float* __restrict__ bias, float* __restrict__ C, int M) {
  __shared__ float As[16][132];
  __shared__ float Ws[16][128];
  const int tid = threadIdx.x;
  const int tx = tid & 15;
  const int ty = tid >> 4;
  const int rowBase = blockIdx.x * 128;
  const int colBase = blockIdx.y * 128;

  float acc[2][2][4][4];
#pragma unroll
  for (int a = 0; a < 2; ++a)
#pragma unroll
    for (int b = 0; b < 2; ++b)
#pragma unroll
      for (int i = 0; i < 4; ++i)
#pragma unroll
        for (int j = 0; j < 4; ++j) acc[a][b][i][j] = 0.f;

  const int NPHASE = HASB ? 2 : 1;
  for (int phase = 0; phase < NPHASE; ++phase) {
    const float* __restrict__ Ain = phase ? B : A;
    const float* __restrict__ Win = phase ? W1 : W0;
    for (int kt = 0; kt < 16; ++kt) {
      const int kb = kt * 16;
#pragma unroll
      for (int l = 0; l < 2; ++l) {
        int idx = tid + l * 256;
        int m = idx >> 2;
        int kq = (idx & 3) * 4;
        int arow = rowBase + m;
        float4 av = make_float4(0.f, 0.f, 0.f, 0.f);
        if (arow < M) av = *reinterpret_cast<const float4*>(&Ain[arow * 256 + kb + kq]);
        As[kq + 0][m] = av.x; As[kq + 1][m] = av.y;
        As[kq + 2][m] = av.z; As[kq + 3][m] = av.w;
      }
#pragma unroll
      for (int l = 0; l < 2; ++l) {
        int idx = tid + l * 256;
        int k = idx >> 5;
        int nq = (idx & 31) * 4;
        float4 wv = *reinterpret_cast<const float4*>(&Win[(kb + k) * 256 + colBase + nq]);
        *reinterpret_cast<float4*>(&Ws[k][nq]) = wv;
      }
      __syncthreads();
#pragma unroll
      for (int k = 0; k < 16; ++k) {
        float4 a0 = *reinterpret_cast<const float4*>(&As[k][ty * 4]);
        float4 a1 = *reinterpret_cast<const float4*>(&As[k][64 + ty * 4]);
        float4 w0 = *reinterpret_cast<const float4*>(&Ws[k][tx * 4]);
        float4 w1 = *reinterpret_cast<const float4*>(&Ws[k][64 + tx * 4]);
        float ar[2][4] = {{a0.x, a0.y, a0.z, a0.w}, {a1.x, a1.y, a1.z, a1.w}};
        float wr[2][4] = {{w0.x, w0.y, w0.z, w0.w}, {w1.x, w1.y, w1.z, w1.w}};
#pragma unroll
        for (int ri = 0; ri < 2; ++ri)
#pragma unroll
          for (int i = 0; i < 4; ++i)
#pragma unroll
            for (int ci = 0; ci < 2; ++ci)
#pragma unroll
              for (int j = 0; j < 4; ++j)
                acc[ri][ci][i][j] = __fmaf_rn(ar[ri][i], wr[ci][j], acc[ri][ci][i][j]);
      }
      __syncthreads();
    }
  }
  float4 bv0 = *reinterpret_cast<const float4*>(&bias[colBase + tx * 4]);
  float4 bv1 = *reinterpret_cast<const float4*>(&bias[colBase + 64 + tx * 4]);
  float bb[2][4] = {{bv0.x, bv0.y, bv0.z, bv0.w}, {bv1.x, bv1.y, bv1.z, bv1.w}};
#pragma unroll
  for (int ri = 0; ri < 2; ++ri) {
#pragma unroll
    for (int i = 0; i < 4; ++i) {
      int row = rowBase + ri * 64 + ty * 4 + i;
      if (row < M) {
#pragma unroll
        for (int ci = 0; ci < 2; ++ci) {
          float4 o;
          o.x = __fadd_rn(acc[ri][ci][i][0], bb[ci][0]);
          o.y = __fadd_rn(acc[ri][ci][i][1], bb[ci][1]);
          o.z = __fadd_rn(acc[ri][ci][i][2], bb[ci][2]);
          o.w = __fadd_rn(acc[ri][ci][i][3], bb[ci][3]);
          if (RELU) {
            o.x = fmaxf(o.x, 0.f); o.y = fmaxf(o.y, 0.f);
            o.z = fmaxf(o.z, 0.f); o.w = fmaxf(o.w, 0.f);
          }
          *reinterpret_cast<float4*>(&C[row * 256 + colBase + ci * 64 + tx * 4]) = o;
        }
      }
    }
  }
}

// ---------------- weight prep: transpose f32 [k][n] -> bf16 [n][k] ------------------
// 16 matrices: m<8 -> w_rel[e*2+l], m>=8 -> w_root. LDS-tiled (pad 258 kills conflicts).
__global__ void k_wprep(const float* __restrict__ w_rel, const float* __restrict__ w_root,
                        bf16_t* __restrict__ WT) {
  __shared__ bf16_t tile[64][258];
  int m = blockIdx.x;
  int k0 = blockIdx.y * 64;
  const float* src = (m < 8) ? (w_rel + (size_t)m * 65536)
                             : (w_root + (size_t)(m - 8) * 65536);
  bf16_t* dst = WT + (size_t)m * 65536;
  int tid = threadIdx.x;   // 256 = n
  for (int r = 0; r < 64; ++r)
    tile[r][tid] = f2bf(src[(k0 + r) * 256 + tid]);
  __syncthreads();
  for (int c = 0; c < 64; c += 8) {
    ushort4 lo, hi;
    lo.x = tile[c + 0][tid]; lo.y = tile[c + 1][tid];
    lo.z = tile[c + 2][tid]; lo.w = tile[c + 3][tid];
    hi.x = tile[c + 4][tid]; hi.y = tile[c + 5][tid];
    hi.z = tile[c + 6][tid]; hi.w = tile[c + 7][tid];
    *reinterpret_cast<ushort4*>(&dst[tid * 256 + k0 + c]) = lo;
    *reinterpret_cast<ushort4*>(&dst[tid * 256 + k0 + c + 4]) = hi;
  }
}

// ---------------- h -> bf16 copy ----------------------------------------------------
__global__ void k_h2b(const float* __restrict__ h, bf16_t* __restrict__ hb) {
  int i = blockIdx.x * 256 + threadIdx.x;          // one float4 each
  if (i < N_NODES * 64) {
    float4 v = *reinterpret_cast<const float4*>(&h[(size_t)i * 4]);
    ushort4 o = make_ushort4(f2bf(v.x), f2bf(v.y), f2bf(v.z), f2bf(v.w));
    *reinterpret_cast<ushort4*>(&hb[(size_t)i * 4]) = o;
  }
}

// ---------------- LDS-free MFMA bf16 GEMM ------------------------------------------
// C = relu(A@W0t^T + B@W1t^T + bias); A,B bf16 [row][k]; Wt bf16 [n][k] (pre-transposed).
// M padded to M_PAD -> no guards. 128x128 tile, 4 waves x 4x4 16x16x32 fragments.
__global__ __launch_bounds__(256) void k_gemm_mfma(
    const bf16_t* __restrict__ A, const bf16_t* __restrict__ W0t,
    const bf16_t* __restrict__ B, const bf16_t* __restrict__ W1t,
    const float* __restrict__ bias, bf16_t* __restrict__ C) {
  const int tid = threadIdx.x;
  const int lane = tid & 63;
  const int wave = tid >> 6;
  const int lm = lane & 15;
  const int quad = lane >> 4;
  const int wm = (wave >> 1) * 64;
  const int wn = (wave & 1) * 64;
  const int rowBase = blockIdx.x * 128;
  const int colBase = blockIdx.y * 128;

  f32x4 acc[4][4];
#pragma unroll
  for (int i = 0; i < 4; ++i)
#pragma unroll
    for (int j = 0; j < 4; ++j) acc[i][j] = (f32x4){0.f, 0.f, 0.f, 0.f};

#pragma unroll
  for (int phase = 0; phase < 2; ++phase) {
    const bf16_t* __restrict__ Ain = phase ? B : A;
    const bf16_t* __restrict__ Wt  = phase ? W1t : W0t;
    const bf16_t* ap[4];
    const bf16_t* bp[4];
#pragma unroll
    for (int i = 0; i < 4; ++i)
      ap[i] = Ain + (size_t)(rowBase + wm + i * 16 + lm) * 256 + quad * 8;
#pragma unroll
    for (int j = 0; j < 4; ++j)
      bp[j] = Wt + (size_t)(colBase + wn + j * 16 + lm) * 256 + quad * 8;
    for (int kt = 0; kt < 8; ++kt) {
      bf16x8 af[4], bfr[4];
#pragma unroll
      for (int i = 0; i < 4; ++i)
        af[i] = *reinterpret_cast<const bf16x8*>(ap[i] + kt * 32);
#pragma unroll
      for (int j = 0; j < 4; ++j)
        bfr[j] = *reinterpret_cast<const bf16x8*>(bp[j] + kt * 32);
#pragma unroll
      for (int i = 0; i < 4; ++i)
#pragma unroll
        for (int j = 0; j < 4; ++j)
          acc[i][j] = __builtin_amdgcn_mfma_f32_16x16x32_bf16(af[i], bfr[j], acc[i][j], 0, 0, 0);
    }
  }
  float bj[4];
#pragma unroll
  for (int j = 0; j < 4; ++j) bj[j] = bias[colBase + wn + j * 16 + lm];
#pragma unroll
  for (int i = 0; i < 4; ++i) {
#pragma unroll
    for (int j = 0; j < 4; ++j) {
      int col = colBase + wn + j * 16 + lm;
#pragma unroll
      for (int r = 0; r < 4; ++r) {
        int row = rowBase + wm + i * 16 + quad * 4 + r;
        C[(size_t)row * 256 + col] = f2bf(fmaxf(acc[i][j][r] + bj[j], 0.f));
      }
    }
  }
}

// ---------------- CSR gather, bf16 in / bf16 out (f32 accumulate) -------------------
__global__ void k_gather(const int* __restrict__ row_start, const int* __restrict__ csr_src,
                         const bf16_t* __restrict__ X, bf16_t* __restrict__ Cout) {
  int tid = threadIdx.x;
  int r = blockIdx.x * 8 + (tid >> 5);     // grid = N/8 exact
  int f = (tid & 31) * 8;
  int j0 = row_start[r], j1 = row_start[r + 1];
  float a[8] = {0.f, 0.f, 0.f, 0.f, 0.f, 0.f, 0.f, 0.f};
  for (int j = j0; j < j1; ++j) {
    int s = csr_src[j];
    bf16x8 v = *reinterpret_cast<const bf16x8*>(&X[(size_t)s * 256 + f]);
#pragma unroll
    for (int t = 0; t < 8; ++t) a[t] += bf2f((unsigned short)v[t]);
  }
  ushort4 lo = make_ushort4(f2bf(a[0]), f2bf(a[1]), f2bf(a[2]), f2bf(a[3]));
  ushort4 hi = make_ushort4(f2bf(a[4]), f2bf(a[5]), f2bf(a[6]), f2bf(a[7]));
  *reinterpret_cast<ushort4*>(&Cout[(size_t)r * 256 + f]) = lo;
  *reinterpret_cast<ushort4*>(&Cout[(size_t)r * 256 + f + 4]) = hi;
}

// ---------------- numpy-faithful f32 router, 4 nodes/block --------------------------
// Arithmetic per (node, col) is BIT-IDENTICAL to r7: ascending-k FMA chain, gf terms,
// bias last, pairwise-8 LN sums, true divisions, f64 exp. Only the data movement
// changed: rt_w1 staged in 32-row LDS chunks shared by 4 waves (4x less L2 traffic).
__global__ __launch_bounds__(256) void k_router_np(
    const float* __restrict__ h, const int* __restrict__ batch,
    const float* __restrict__ gf, const float* __restrict__ lnn,
    const float* __restrict__ rtw1, const float* __restrict__ rtb1,
    const float* __restrict__ lng, const float* __restrict__ lnb,
    const float* __restrict__ rtw2, const float* __restrict__ rtb2,
    const float* __restrict__ centers, float* __restrict__ sw) {
  __shared__ float sh[4][256];
  __shared__ float wt[32][128];
  __shared__ float sr[4][128];
  __shared__ float sa[4][128];
  __shared__ float sb[4][8];
  const int tid = threadIdx.x;
  const int w = tid >> 6;
  const int l = tid & 63;
  const int node = blockIdx.x * 4 + w;     // grid = N/4 exact

#pragma unroll
  for (int j = 0; j < 4; ++j) sh[w][l + 64 * j] = h[(size_t)node * 256 + l + 64 * j];

  int g = batch[node];
  float gf0 = gf[g * 2 + 0], gf1 = gf[g * 2 + 1], nl = lnn[g];

  float acc0 = 0.f, acc1 = 0.f;
  for (int c = 0; c < 8; ++c) {
    __syncthreads();
    for (int i = tid; i < 1024; i += 256) {          // 32 rows x 128 cols as float4
      int kk = i >> 5;
      int n4 = (i & 31) * 4;
      *reinterpret_cast<float4*>(&wt[kk][n4]) =
          *reinterpret_cast<const float4*>(&rtw1[(c * 32 + kk) * RHD + n4]);
    }
    __syncthreads();
#pragma unroll 4
    for (int kk = 0; kk < 32; ++kk) {
      float hv = sh[w][c * 32 + kk];
      acc0 = __fmaf_rn(hv, wt[kk][l], acc0);
      acc1 = __fmaf_rn(hv, wt[kk][l + 64], acc1);
    }
  }
  acc0 = __fmaf_rn(gf0, rtw1[256 * RHD + l], acc0);
  acc0 = __fmaf_rn(gf1, rtw1[257 * RHD + l], acc0);
  acc1 = __fmaf_rn(gf0, rtw1[256 * RHD + l + 64], acc1);
  acc1 = __fmaf_rn(gf1, rtw1[257 * RHD + l + 64], acc1);
  float r0 = __fadd_rn(acc0, rtb1[l]);
  float r1 = __fadd_rn(acc1, rtb1[l + 64]);
  sr[w][l] = r0; sr[w][l + 64] = r1;
  __syncthreads();

  if (l == 0) {
    float a[8];
#pragma unroll
    for (int j = 0; j < 8; ++j) a[j] = sr[w][j];
    for (int i = 8; i < 128; i += 8)
#pragma unroll
      for (int j = 0; j < 8; ++j) a[j] = __fadd_rn(a[j], sr[w][i + j]);
    sb[w][0] = __fdiv_rn(tree8(a), 128.0f);
  }
  __syncthreads();
  float mu = sb[w][0];
  float d0 = __fsub_rn(r0, mu), d1 = __fsub_rn(r1, mu);
  sr[w][l] = __fmul_rn(d0, d0);
  sr[w][l + 64] = __fmul_rn(d1, d1);
  __syncthreads();
  if (l == 0) {
    float a[8];
#pragma unroll
    for (int j = 0; j < 8; ++j) a[j] = sr[w][j];
    for (int i = 8; i < 128; i += 8)
#pragma unroll
      for (int j = 0; j < 8; ++j) a[j] = __fadd_rn(a[j], sr[w][i + j]);
    sb[w][1] = __fdiv_rn(tree8(a), 128.0f);
  }
  __syncthreads();
  float var = sb[w][1];
  float inv = __fdiv_rn(1.0f, sqrtf(__fadd_rn(var, 1e-5f)));
  float y0 = __fadd_rn(__fmul_rn(__fmul_rn(d0, inv), lng[l]), lnb[l]);
  float y1 = __fadd_rn(__fmul_rn(__fmul_rn(d1, inv), lng[l + 64]), lnb[l + 64]);
  sa[w][l] = fmaxf(y0, 0.f);
  sa[w][l + 64] = fmaxf(y1, 0.f);
  __syncthreads();

  if (l < 4) {
    float acc = 0.f;
    for (int k = 0; k < 128; ++k) acc = __fmaf_rn(sa[w][k], rtw2[k * 4 + l], acc);
    float lrn = __fadd_rn(acc, rtb2[l]);
    float dd = __fsub_rn(nl, centers[l]);
    float pr = -__fmul_rn(dd, dd);
    sb[w][4 + l] = __fadd_rn(__fmul_rn(0.65f, lrn), __fmul_rn(0.35f, pr));
  }
  __syncthreads();

  if (l == 0) {
    float lg[4] = {sb[w][4], sb[w][5], sb[w][6], sb[w][7]};
    float mx = fmaxf(fmaxf(lg[0], lg[1]), fmaxf(lg[2], lg[3]));
    float e[4];
#pragma unroll
    for (int c = 0; c < 4; ++c)
      e[c] = (float)exp((double)__fsub_rn(lg[c], mx));
    float S = __fadd_rn(__fadd_rn(__fadd_rn(e[0], e[1]), e[2]), e[3]);
    float p[4];
#pragma unroll
    for (int c = 0; c < 4; ++c) p[c] = __fdiv_rn(e[c], S);
    int i1 = 0;
#pragma unroll
    for (int c = 1; c < 4; ++c) if (p[c] > p[i1]) i1 = c;
    int i2 = -1;
#pragma unroll
    for (int c = 0; c < 4; ++c) {
      if (c == i1) continue;
      if (i2 < 0 || p[c] > p[i2]) i2 = c;
    }
    float den = __fadd_rn(__fadd_rn(p[i1], p[i2]), 1e-8f);
    float swv[4] = {0.f, 0.f, 0.f, 0.f};
    swv[i1] = __fdiv_rn(p[i1], den);
    swv[i2] = __fdiv_rn(p[i2], den);
    *reinterpret_cast<float4*>(&sw[node * 4]) =
        make_float4(swv[0], swv[1], swv[2], swv[3]);
  }
}

// ---------------- output head (bf16 inputs) ----------------------------------------
template <bool ACC>
__global__ void k_out(const bf16_t* __restrict__ A2, const bf16_t* __restrict__ X2,
                      const float* __restrict__ wro, const float* __restrict__ bro,
                      const float* __restrict__ wto, const float* __restrict__ sw,
                      float* __restrict__ out, int e) {
  int tid = threadIdx.x;
  int r = blockIdx.x * 4 + (tid >> 6);
  int lane = tid & 63;
  int k0 = lane * 4;
  float wr_[24], wt_[24];
#pragma unroll
  for (int q = 0; q < 6; ++q) {
    float4 a = *reinterpret_cast<const float4*>(&wro[k0 * 6 + q * 4]);
    wr_[q * 4 + 0] = a.x; wr_[q * 4 + 1] = a.y; wr_[q * 4 + 2] = a.z; wr_[q * 4 + 3] = a.w;
    float4 b = *reinterpret_cast<const float4*>(&wto[k0 * 6 + q * 4]);
    wt_[q * 4 + 0] = b.x; wt_[q * 4 + 1] = b.y; wt_[q * 4 + 2] = b.z; wt_[q * 4 + 3] = b.w;
  }
  ushort4 av4 = *reinterpret_cast<const ushort4*>(&A2[(size_t)r * 256 + k0]);
  ushort4 xv4 = *reinterpret_cast<const ushort4*>(&X2[(size_t)r * 256 + k0]);
  float av[4] = {bf2f(av4.x), bf2f(av4.y), bf2f(av4.z), bf2f(av4.w)};
  float xv[4] = {bf2f(xv4.x), bf2f(xv4.y), bf2f(xv4.z), bf2f(xv4.w)};
  float p[6] = {0.f, 0.f, 0.f, 0.f, 0.f, 0.f};
#pragma unroll
  for (int jj = 0; jj < 4; ++jj)
#pragma unroll
    for (int c = 0; c < 6; ++c)
      p[c] += av[jj] * wr_[jj * 6 + c] + xv[jj] * wt_[jj * 6 + c];
#pragma unroll
  for (int off = 32; off > 0; off >>= 1)
#pragma unroll
    for (int c = 0; c < 6; ++c) p[c] += __shfl_down(p[c], off, 64);
  if (lane == 0) {
    float s = sw[r * 4 + e];
#pragma unroll
    for (int c = 0; c < 6; ++c) {
      float v = s * (p[c] + bro[c]);
      if (ACC) out[r * 6 + c] += v;
      else out[r * 6 + c] = v;
    }
  }
}

// ---------------- launch ----------------
extern "C" void kernel_launch(void* const* d_in, const int* in_sizes, int n_in,
                              void* d_out, int out_size, void* d_ws, size_t ws_size,
                              hipStream_t stream) {
  const float* x        = (const float*)d_in[0];
  const int*   edge     = (const int*)d_in[1];
  const int*   batch    = (const int*)d_in[2];
  const float* enc_w1   = (const float*)d_in[4];
  const float* enc_b1   = (const float*)d_in[5];
  const float* enc_w2   = (const float*)d_in[6];
  const float* enc_b2   = (const float*)d_in[7];
  const float* rt_w1    = (const float*)d_in[8];
  const float* rt_b1    = (const float*)d_in[9];
  const float* ln_g     = (const float*)d_in[10];
  const float* ln_b     = (const float*)d_in[11];
  const float* rt_w2    = (const float*)d_in[12];
  const float* rt_b2    = (const float*)d_in[13];
  const float* centers  = (const float*)d_in[14];
  const float* w_rel    = (const float*)d_in[15];
  const float* b_rel    = (const float*)d_in[16];
  const float* w_root   = (const float*)d_in[17];
  const float* w_relo   = (const float*)d_in[18];
  const float* b_relo   = (const float*)d_in[19];
  const float* w_rooto  = (const float*)d_in[20];
  float* out = (float*)d_out;

  char* wsp = (char*)d_ws;
  auto alloc = [&](size_t bytes) -> char* {
    char* p = wsp;
    wsp += (bytes + 255) & ~(size_t)255;
    return p;
  };
  const size_t actF32 = (size_t)M_PAD * 256 * sizeof(float);   // 51.25 MB
  const size_t actB16 = (size_t)M_PAD * 256 * sizeof(bf16_t);  // 25.6 MB
  float*  h   = (float*)alloc(actF32);
  // t (f32 encoder intermediate) aliases the X1+X2 bf16 region: t is dead before
  // X1 is first written (expert GEMM), and X1/X2 are dead before the next call.
  char*   tx  = alloc(actF32);
  float*  t   = (float*)tx;
  bf16_t* X1  = (bf16_t*)tx;
  bf16_t* X2  = (bf16_t*)(tx + actB16);
  bf16_t* A1  = (bf16_t*)alloc(actB16);
  bf16_t* AGG = (bf16_t*)alloc(actB16);
  bf16_t* hb  = (bf16_t*)alloc(actB16);
  bf16_t* WT  = (bf16_t*)alloc((size_t)16 * 65536 * sizeof(bf16_t));  // 2 MB
  float* swp  = (float*)alloc((size_t)N_NODES * 4 * sizeof(float));
  int*   n_cnt = (int*)alloc(NG * sizeof(int));
  int*   e_cnt = (int*)alloc(NG * sizeof(int));
  float* gfbuf = (float*)alloc(NG * 2 * sizeof(float));
  float* lnn   = (float*)alloc(NG * sizeof(float));
  int* deg       = (int*)alloc((size_t)N_NODES * sizeof(int));
  int* row_start = (int*)alloc((size_t)(N_NODES + 1) * sizeof(int));
  int* cursor    = (int*)alloc((size_t)N_NODES * sizeof(int));
  int* csr_src   = (int*)alloc((size_t)NUM_EDGES * sizeof(int));

  // graph stats + CSR build + weight prep
  k_zero<<<(N_NODES + 255) / 256, 256, 0, stream>>>(deg, n_cnt, e_cnt);
  k_count_nodes<<<(N_NODES + 255) / 256, 256, 0, stream>>>(batch, n_cnt);
  k_count_edges<<<(NUM_EDGES + 255) / 256, 256, 0, stream>>>(edge, batch, e_cnt, deg);
  k_graph_stats<<<1, 64, 0, stream>>>(n_cnt, e_cnt, gfbuf, lnn);
  k_scan<<<1, 1024, 0, stream>>>(deg, row_start, cursor);
  k_fill<<<(NUM_EDGES + 255) / 256, 256, 0, stream>>>(edge, cursor, csr_src);
  dim3 wgrid(16, 4);
  k_wprep<<<wgrid, 256, 0, stream>>>(w_rel, w_root, WT);

  // encoder (fp32 SIMT, frozen -> h bit-identical for router)
  k_enc1<<<(N_NODES + 15) / 16, 256, 0, stream>>>(x, enc_w1, enc_b1, t);
  dim3 ggrid(M_PAD / 128, 2);
  k_gemm<false, false><<<ggrid, 256, 0, stream>>>(t, enc_w2, nullptr, nullptr, enc_b2, h, N_NODES);

  // router (np-faithful, 4 nodes/block)
  k_router_np<<<N_NODES / 4, 256, 0, stream>>>(
      h, batch, gfbuf, lnn, rt_w1, rt_b1, ln_g, ln_b, rt_w2, rt_b2, centers, swp);

  // bf16 copy of h + loop-invariant agg_h
  k_h2b<<<(N_NODES * 64 + 255) / 256, 256, 0, stream>>>(h, hb);
  k_gather<<<N_NODES / 8, 256, 0, stream>>>(row_start, csr_src, hb, AGG);

  // experts: LDS-free MFMA bf16 GEMMs
  for (int e = 0; e < NEXP; ++e) {
    const bf16_t* wr0 = WT + (size_t)(e * 2 + 0) * 65536;
    const bf16_t* wr1 = WT + (size_t)(e * 2 + 1) * 65536;
    const bf16_t* wo0 = WT + (size_t)(8 + e * 2 + 0) * 65536;
    const bf16_t* wo1 = WT + (size_t)(8 + e * 2 + 1) * 65536;
    const float* br0 = b_rel + (size_t)(e * 2 + 0) * 256;
    const float* br1 = b_rel + (size_t)(e * 2 + 1) * 256;
    k_gemm_mfma<<<ggrid, 256, 0, stream>>>(AGG, wr0, hb, wo0, br0, X1);
    k_gather<<<N_NODES / 8, 256, 0, stream>>>(row_start, csr_src, X1, A1);
    k_gemm_mfma<<<ggrid, 256, 0, stream>>>(A1, wr1, X1, wo1, br1, X2);
    k_gather<<<N_NODES / 8, 256, 0, stream>>>(row_start, csr_src, X2, A1);
    const float* wro = w_relo  + (size_t)e * 256 * OUTD;
    const float* bro = b_relo  + (size_t)e * OUTD;
    const float* wto = w_rooto + (size_t)e * 256 * OUTD;
    if (e == 0)
      k_out<false><<<N_NODES / 4, 256, 0, stream>>>(A1, X2, wro, bro, wto, swp, out, e);
    else
      k_out<true><<<N_NODES / 4, 256, 0, stream>>>(A1, X2, wro, bro, wto, swp, out, e);
  }
}